// Round 6
// baseline (1448.423 us; speedup 1.0000x reference)
//
#include <hip/hip_runtime.h>
#include <hip/hip_bf16.h>

#define KD 4096
#define ND 11008
#define MD 16384
#define KGD 32
#define NT (KD / 64)

typedef __hip_bfloat16 bf16;
typedef float f32x4 __attribute__((ext_vector_type(4)));
typedef short bf16x8 __attribute__((ext_vector_type(8)));

#define WAITV(n) asm volatile("s_waitcnt vmcnt(" #n ")" ::: "memory")
#define BAR()    asm volatile("s_barrier" ::: "memory")
#define LGKM0()  asm volatile("s_waitcnt lgkmcnt(0)" ::: "memory")

__device__ __forceinline__ void gload16(const bf16* g, bf16* l) {
    __builtin_amdgcn_global_load_lds((const __attribute__((address_space(1))) void*)g,
                                     (__attribute__((address_space(3))) void*)l, 16, 0, 0);
}

// ---------------------------------------------------------------------------
// x: fp32 -> bf16 (8 elems/thread)
// ---------------------------------------------------------------------------
__global__ void cvt_kernel(const float* __restrict__ x, bf16* __restrict__ y, int n8) {
    int i = blockIdx.x * blockDim.x + threadIdx.x;
    if (i >= n8) return;
    const f32x4* p = reinterpret_cast<const f32x4*>(x + (size_t)i * 8);
    f32x4 a = p[0], b = p[1];
    bf16 o[8];
#pragma unroll
    for (int e = 0; e < 4; ++e) {
        o[e]     = __float2bfloat16(a[e]);
        o[4 + e] = __float2bfloat16(b[e]);
    }
    *reinterpret_cast<bf16x8*>(y + (size_t)i * 8) = *reinterpret_cast<bf16x8*>(o);
}

// ---------------------------------------------------------------------------
// dequant packed int4 -> bf16 rows [n0 .. n0+rows) into wd (chunk-local)
// ---------------------------------------------------------------------------
__global__ void dequant_kernel(const int* __restrict__ wp, const float* __restrict__ sc,
                               bf16* __restrict__ wd, int n0, int rows) {
    const int per_row = KD / 8;
    int t = blockIdx.x * blockDim.x + threadIdx.x;
    if (t >= rows * per_row) return;
    int lr = t / per_row;
    int q  = t - lr * per_row;
    int n  = n0 + lr;
    int j  = q * 4;
    const int4 p = *reinterpret_cast<const int4*>(wp + (size_t)n * (KD / 2) + j);
    float s = sc[(size_t)n * KGD + (j >> 6)];
    int v[4] = {p.x, p.y, p.z, p.w};
    bf16 o[8];
#pragma unroll
    for (int i = 0; i < 4; ++i) {
        o[2 * i]     = __float2bfloat16((float)((v[i] & 0xF) - 8) * s);
        o[2 * i + 1] = __float2bfloat16((float)(((v[i] >> 4) & 0xF) - 8) * s);
    }
    *reinterpret_cast<bf16x8*>(wd + (size_t)lr * KD + j * 2) = *reinterpret_cast<bf16x8*>(o);
}

// ---------------------------------------------------------------------------
// GEMM: C[M,N] = A[M,K] * B[N,K]^T, bf16 in, fp32 out.
// 256x256 tile, BK=64 (two K=32 halves kh), 512 thr / 8 waves (2M x 4N),
// per-wave out 128x64. 8-phase m201-style schedule: per phase
// {4-8 ds_read_b128 || 2 global_load_lds || barrier || lgkmcnt(0) ||
//  setprio(1) 16 MFMA setprio(0) || [vmcnt(6) at P4/P8] || barrier}.
// Stage ledger: each (buf,kh,op) region staged 1 phase after its last read,
// consumed 7 phases later; vmcnt(6) at P4/P8 guarantees landing with >=1
// barrier before the dependent ds_reads. Conflict-free swizzle (0 conflicts).
// ---------------------------------------------------------------------------
__global__ __launch_bounds__(512, 2) void gemm256(const bf16* __restrict__ A,
                                                  const bf16* __restrict__ B,
                                                  float* __restrict__ C,
                                                  int mtiles, int ntiles, int n0base) {
    __shared__ bf16 lds[2][2][2][8192];  // [buf][kh][op(A/B)][256 rows x 32 k, swizzled]
    const int tid  = threadIdx.x;
    const int lane = tid & 63;
    const int w    = tid >> 6;

    // bijective XCD-aware block swizzle
    int nwg = mtiles * ntiles;
    int orig = blockIdx.x;
    int q8 = nwg >> 3, r8 = nwg & 7;
    int xcd = orig & 7, off = orig >> 3;
    int wg = (xcd < r8 ? xcd * (q8 + 1) : r8 * (q8 + 1) + (xcd - r8) * q8) + off;
    const int mb = wg / ntiles, nb = wg - mb * ntiles;
    const int m0 = mb * 256, n0 = nb * 256;

    const int wm = w >> 2, wn = w & 3;
    const int rl = lane & 15, kq = lane >> 4;
    const int sz = (rl >> 1) & 3;
    const int ro = 8 * (kq ^ sz);          // swizzled k-chunk for ds_read

    // staging source (per-lane pre-swizzle so linear LDS dest == swizzled layout)
    const int src_c = (((lane & 3) ^ ((lane >> 3) & 3)) << 3);
    const int src_r = (w << 4) + (lane >> 2);
    const bf16* Abase = A + (size_t)(m0 + src_r) * KD + src_c;
    const bf16* Bbase = B + (size_t)(n0 + src_r) * KD + src_c;

    f32x4 acc[8][4] = {};
    bf16x8 afr[4], bfr[4];

    auto stA = [&](int b, int k, int k0) {
        const bf16* ga = Abase + k0 + k * 32;
        bf16* la = &lds[b][k][0][w * 512];
        gload16(ga, la);
        gload16(ga + (size_t)128 * KD, la + 4096);
    };
    auto stB = [&](int b, int k, int k0) {
        const bf16* gb = Bbase + k0 + k * 32;
        bf16* lb = &lds[b][k][1][w * 512];
        gload16(gb, lb);
        gload16(gb + (size_t)128 * KD, lb + 4096);
    };

#define PHASE_A(bufi, khi, STAGE, VM) do {                                          \
    const bf16* ua_ = &lds[bufi][khi][0][0];                                        \
    const bf16* ub_ = &lds[bufi][khi][1][0];                                        \
    _Pragma("unroll") for (int m_ = 0; m_ < 4; ++m_)                                \
        afr[m_] = *reinterpret_cast<const bf16x8*>(                                 \
            &ua_[(wm * 128 + m_ * 16 + rl) * 32 + ro]);                             \
    _Pragma("unroll") for (int n_ = 0; n_ < 4; ++n_)                                \
        bfr[n_] = *reinterpret_cast<const bf16x8*>(                                 \
            &ub_[(wn * 64 + n_ * 16 + rl) * 32 + ro]);                              \
    STAGE;                                                                          \
    BAR(); LGKM0();                                                                 \
    __builtin_amdgcn_s_setprio(1);                                                  \
    _Pragma("unroll") for (int m_ = 0; m_ < 4; ++m_)                                \
        _Pragma("unroll") for (int n_ = 0; n_ < 4; ++n_)                            \
            acc[m_][n_] = __builtin_amdgcn_mfma_f32_16x16x32_bf16(                  \
                afr[m_], bfr[n_], acc[m_][n_], 0, 0, 0);                            \
    __builtin_amdgcn_s_setprio(0);                                                  \
    VM; BAR();                                                                      \
} while (0)

#define PHASE_B(bufi, khi, STAGE, VM) do {                                          \
    const bf16* ua_ = &lds[bufi][khi][0][0];                                        \
    _Pragma("unroll") for (int m_ = 0; m_ < 4; ++m_)                                \
        afr[m_] = *reinterpret_cast<const bf16x8*>(                                 \
            &ua_[(wm * 128 + (4 + m_) * 16 + rl) * 32 + ro]);                       \
    STAGE;                                                                          \
    BAR(); LGKM0();                                                                 \
    __builtin_amdgcn_s_setprio(1);                                                  \
    _Pragma("unroll") for (int m_ = 0; m_ < 4; ++m_)                                \
        _Pragma("unroll") for (int n_ = 0; n_ < 4; ++n_)                            \
            acc[4 + m_][n_] = __builtin_amdgcn_mfma_f32_16x16x32_bf16(              \
                afr[m_], bfr[n_], acc[4 + m_][n_], 0, 0, 0);                        \
    __builtin_amdgcn_s_setprio(0);                                                  \
    VM; BAR();                                                                      \
} while (0)

    // prologue: tile0 all 4 units, tile1 first 3 units (A(1,1) staged at P1 of j=0)
    stB(0, 0, 0); stA(0, 0, 0); stB(0, 1, 0); stA(0, 1, 0);
    stB(1, 0, 64); stA(1, 0, 64); stB(1, 1, 64);
    WAITV(6);  // 14 outstanding -> oldest 8 (tile0) landed
    BAR();

    for (int j = 0; j < NT / 2 - 1; ++j) {
        const int t1 = (2 * j + 1) * 64, t2 = (2 * j + 2) * 64, t3 = (2 * j + 3) * 64;
        PHASE_A(0, 0, stA(1, 1, t1), (void)0);
        PHASE_B(0, 0, stB(0, 0, t2), (void)0);
        PHASE_A(0, 1, stA(0, 0, t2), (void)0);
        PHASE_B(0, 1, stB(0, 1, t2), WAITV(6));
        PHASE_A(1, 0, stA(0, 1, t2), (void)0);
        PHASE_B(1, 0, stB(1, 0, t3), (void)0);
        PHASE_A(1, 1, stA(1, 0, t3), (void)0);
        PHASE_B(1, 1, stB(1, 1, t3), WAITV(6));
    }
    // epilogue: tiles NT-2 (buf0), NT-1 (buf1); only P1 stages (A(1,1) of last tile)
    PHASE_A(0, 0, stA(1, 1, (NT - 1) * 64), (void)0);
    PHASE_B(0, 0, (void)0, (void)0);
    PHASE_A(0, 1, (void)0, (void)0);
    PHASE_B(0, 1, (void)0, WAITV(6));
    PHASE_A(1, 0, (void)0, WAITV(4));
    PHASE_B(1, 0, (void)0, WAITV(2));
    PHASE_A(1, 1, (void)0, WAITV(0));
    PHASE_B(1, 1, (void)0, (void)0);

#undef PHASE_A
#undef PHASE_B

    // epilogue: C/D layout col=lane&15, row=(lane>>4)*4+r ; fp32 out
    const int crow = m0 + wm * 128 + kq * 4;
    const int ccol = n0base + n0 + wn * 64 + rl;
#pragma unroll
    for (int mi = 0; mi < 8; ++mi) {
#pragma unroll
        for (int r = 0; r < 4; ++r) {
            float* cp = C + (size_t)(crow + mi * 16 + r) * ND + ccol;
#pragma unroll
            for (int ni = 0; ni < 4; ++ni)
                cp[ni * 16] = acc[mi][ni][r];
        }
    }
}

extern "C" void kernel_launch(void* const* d_in, const int* in_sizes, int n_in,
                              void* d_out, int out_size, void* d_ws, size_t ws_size,
                              hipStream_t stream) {
    const float* x  = (const float*)d_in[0];
    const int*   wp = (const int*)d_in[1];
    const float* sc = (const float*)d_in[2];
    float* out = (float*)d_out;

    // partition ws into x-bf16 chunk (mc rows) + W-bf16 chunk (nc rows), both x256
    long long rows_cap = (long long)(ws_size / ((size_t)KD * 2));
    int mc, nc;
    if (rows_cap >= MD + 256) {
        mc = MD;
        long long r = rows_cap - MD;
        nc = (int)((r / 256) * 256);
        if (nc > ND) nc = ND;
    } else if (rows_cap >= ND + 256) {
        nc = ND;
        long long r = rows_cap - ND;
        mc = (int)((r / 256) * 256);
        if (mc > MD) mc = MD;
    } else {
        nc = (int)(((rows_cap / 2) / 256) * 256);
        if (nc > ND) nc = ND;
        long long r = rows_cap - nc;
        mc = (int)((r / 256) * 256);
        if (mc > MD) mc = MD;
        if (mc <= 0 || nc <= 0) return;
    }

    bf16* xbuf = (bf16*)d_ws;
    bf16* wbuf = xbuf + (size_t)mc * KD;

    for (int m0 = 0; m0 < MD; m0 += mc) {
        int mrows = (MD - m0 < mc) ? (MD - m0) : mc;   // multiple of 256
        int n8 = mrows * (KD / 8);
        cvt_kernel<<<(n8 + 255) / 256, 256, 0, stream>>>(x + (size_t)m0 * KD, xbuf, n8);
        for (int n0 = 0; n0 < ND; n0 += nc) {
            int nrows = (ND - n0 < nc) ? (ND - n0) : nc;  // multiple of 256
            int tt = nrows * (KD / 8);
            dequant_kernel<<<(tt + 255) / 256, 256, 0, stream>>>(wp, sc, wbuf, n0, nrows);
            int mt = mrows / 256, nt2 = nrows / 256;
            gemm256<<<mt * nt2, 512, 0, stream>>>(xbuf, wbuf, out + (size_t)m0 * ND, mt, nt2, n0);
        }
    }
}